// Round 4
// baseline (98.288 us; speedup 1.0000x reference)
//
#include <hip/hip_runtime.h>

// VectorQuantizer forward:
//   x          [64,32,32,64] f32  -> flat [N=65536, D=64]
//   embeddings [D=64, K=512] f32  (codes are COLUMNS)
//   out        = x + (q - x)  where q = column argmin_k ||f - e_k||^2
//   loss       = (1 + 0.25) * mean((q - x)^2)
// d_out = [out (4194304 f32), loss (1 f32)]
//
// Structure: codebook staged in LDS (128KB, 1 block/CU), uniform ds_read
// broadcast in the scan loop, 2 rows/thread so one ds_read_b128 feeds 16
// FMAs. K-split x4 across 2-wave groups, packed u64 argmin combine.

#define N_ROWS 65536
#define DIM 64
#define KCODES 512
#define KGROUPS 4
#define KCHUNK 128           // codes per 2-wave group
#define ROWS_PER_BLOCK 256   // 128 lanes/group x 2 rows/thread
#define THREADS 512

// ws layout (bytes):
//   [0,8)      double loss accumulator
//   [256,2304) en2[512] f32
//   [4096, 4096+131072) eT[512][64] f32

__global__ void vq_prep(const float* __restrict__ emb, float* __restrict__ ws_f,
                        double* __restrict__ ws_d) {
    int k = threadIdx.x;  // 512 threads, one per code
    if (k == 0) ws_d[0] = 0.0;
    float* en2 = ws_f + 64;    // byte offset 256
    float* eT  = ws_f + 1024;  // byte offset 4096
    float s = 0.0f;
    #pragma unroll
    for (int d = 0; d < DIM; ++d) {
        float v = emb[d * KCODES + k];   // coalesced across k
        eT[k * DIM + d] = v;
        s = fmaf(v, v, s);
    }
    en2[k] = s;
}

__global__ __launch_bounds__(THREADS, 2)
void vq_main(const float* __restrict__ x, const float* __restrict__ ws_f,
             float* __restrict__ out, double* __restrict__ loss_acc) {
    // 131072 + 2048 + 8192 = 141312 B of LDS -> 1 block/CU.
    __shared__ float eTs[KCODES * DIM];
    __shared__ float en2s[KCODES];
    __shared__ unsigned long long sm[KGROUPS][ROWS_PER_BLOCK];

    const int tid  = threadIdx.x;                               // 0..511
    const int g    = __builtin_amdgcn_readfirstlane(tid >> 7);  // K-group 0..3 (2 waves each)
    const int lr   = tid & 127;
    const int row0 = blockIdx.x * ROWS_PER_BLOCK + lr;
    const int row1 = row0 + 128;

    // Two rows of x into registers (32 x float4 = 128 f32).
    const float4* xr0 = (const float4*)(x + (size_t)row0 * DIM);
    const float4* xr1 = (const float4*)(x + (size_t)row1 * DIM);
    float4 f0[16], f1[16];
    #pragma unroll
    for (int j = 0; j < 16; ++j) { f0[j] = xr0[j]; f1[j] = xr1[j]; }

    // Stage codebook into LDS with XOR-swizzled STORAGE (dim-block j of code k
    // lands at float4-slot k*16 + (j ^ (k&7))). Reads below undo the swizzle,
    // so accumulation order (and thus FP rounding) is identical to the
    // unswizzled, previously-validated version.
    {
        const float4* src = (const float4*)(ws_f + 1024);
        float4* dst = (float4*)eTs;
        #pragma unroll
        for (int i = 0; i < 16; ++i) {
            const int idx = i * THREADS + tid;
            dst[idx ^ ((idx >> 4) & 7)] = src[idx];
        }
        if (tid < 128) ((float4*)en2s)[tid] = ((const float4*)(ws_f + 64))[tid];
    }
    __syncthreads();

    // r2 = ||f||^2 per row.
    float4 a0 = make_float4(0.f, 0.f, 0.f, 0.f);
    float4 a1 = make_float4(0.f, 0.f, 0.f, 0.f);
    #pragma unroll
    for (int j = 0; j < 16; ++j) {
        a0.x = fmaf(f0[j].x, f0[j].x, a0.x); a0.y = fmaf(f0[j].y, f0[j].y, a0.y);
        a0.z = fmaf(f0[j].z, f0[j].z, a0.z); a0.w = fmaf(f0[j].w, f0[j].w, a0.w);
        a1.x = fmaf(f1[j].x, f1[j].x, a1.x); a1.y = fmaf(f1[j].y, f1[j].y, a1.y);
        a1.z = fmaf(f1[j].z, f1[j].z, a1.z); a1.w = fmaf(f1[j].w, f1[j].w, a1.w);
    }
    const float r2_0 = (a0.x + a0.y) + (a0.z + a0.w);
    const float r2_1 = (a1.x + a1.y) + (a1.z + a1.w);

    // Scan this group's K-chunk. Uniform LDS address -> broadcast read.
    const float4* eTs4 = (const float4*)eTs;
    float best0 = 3.402823466e38f, best1 = 3.402823466e38f;
    int   bk0 = 0, bk1 = 0;
    const int kbase = g * KCHUNK;
    #pragma unroll 2
    for (int kk = 0; kk < KCHUNK; ++kk) {
        const int k = kbase + kk;
        const int ebase = k * 16;
        const int c = k & 7;
        float4 acc0 = make_float4(0.f, 0.f, 0.f, 0.f);
        float4 acc1 = make_float4(0.f, 0.f, 0.f, 0.f);
        #pragma unroll
        for (int j = 0; j < 16; ++j) {
            const float4 e = eTs4[ebase + (j ^ c)];   // dim-block j (de-swizzled)
            acc0.x = fmaf(f0[j].x, e.x, acc0.x); acc0.y = fmaf(f0[j].y, e.y, acc0.y);
            acc0.z = fmaf(f0[j].z, e.z, acc0.z); acc0.w = fmaf(f0[j].w, e.w, acc0.w);
            acc1.x = fmaf(f1[j].x, e.x, acc1.x); acc1.y = fmaf(f1[j].y, e.y, acc1.y);
            acc1.z = fmaf(f1[j].z, e.z, acc1.z); acc1.w = fmaf(f1[j].w, e.w, acc1.w);
        }
        const float dot0 = (acc0.x + acc0.y) + (acc0.z + acc0.w);
        const float dot1 = (acc1.x + acc1.y) + (acc1.z + acc1.w);
        const float en = en2s[k];
        const float s0 = (r2_0 + en) - 2.0f * dot0;
        const float s1 = (r2_1 + en) - 2.0f * dot1;
        if (s0 < best0) { best0 = s0; bk0 = k; }   // strict <: first index wins
        if (s1 < best1) { best1 = s1; bk1 = k; }
    }

    // Packed (distance bits, index): distances are positive -> bit-monotone;
    // idx in low bits makes exact ties resolve to the lowest index.
    sm[g][lr] = ((unsigned long long)__float_as_uint(best0) << 32) | (unsigned)bk0;
    sm[g][lr + 128] = ((unsigned long long)__float_as_uint(best1) << 32) | (unsigned)bk1;
    __syncthreads();

    if (g == 0) {
        unsigned long long q0 = sm[0][lr];
        unsigned long long q1 = sm[0][lr + 128];
        #pragma unroll
        for (int t = 1; t < KGROUPS; ++t) {
            const unsigned long long u0 = sm[t][lr];       if (u0 < q0) q0 = u0;
            const unsigned long long u1 = sm[t][lr + 128]; if (u1 < q1) q1 = u1;
        }
        const int bidx0 = (int)(q0 & 0xffffffffull);
        const int bidx1 = (int)(q1 & 0xffffffffull);

        // Gather codes from LDS (swizzle spreads lanes across banks),
        // write out = x + (q - x), accumulate loss.
        const int eb0 = bidx0 * 16, c0 = bidx0 & 7;
        const int eb1 = bidx1 * 16, c1 = bidx1 & 7;
        float4* o40 = (float4*)(out + (size_t)row0 * DIM);
        float4* o41 = (float4*)(out + (size_t)row1 * DIM);
        float lsum = 0.0f;
        #pragma unroll
        for (int j = 0; j < 16; ++j) {
            float4 q = eTs4[eb0 + (j ^ c0)];
            float4 xv = f0[j];
            float4 o; float dx;
            dx = q.x - xv.x; o.x = xv.x + dx; lsum = fmaf(dx, dx, lsum);
            dx = q.y - xv.y; o.y = xv.y + dx; lsum = fmaf(dx, dx, lsum);
            dx = q.z - xv.z; o.z = xv.z + dx; lsum = fmaf(dx, dx, lsum);
            dx = q.w - xv.w; o.w = xv.w + dx; lsum = fmaf(dx, dx, lsum);
            o40[j] = o;
        }
        #pragma unroll
        for (int j = 0; j < 16; ++j) {
            float4 q = eTs4[eb1 + (j ^ c1)];
            float4 xv = f1[j];
            float4 o; float dx;
            dx = q.x - xv.x; o.x = xv.x + dx; lsum = fmaf(dx, dx, lsum);
            dx = q.y - xv.y; o.y = xv.y + dx; lsum = fmaf(dx, dx, lsum);
            dx = q.z - xv.z; o.z = xv.z + dx; lsum = fmaf(dx, dx, lsum);
            dx = q.w - xv.w; o.w = xv.w + dx; lsum = fmaf(dx, dx, lsum);
            o41[j] = o;
        }

        // Wave-level reduction of loss in double, one atomic per wave.
        double dl = (double)lsum;
        #pragma unroll
        for (int off = 32; off > 0; off >>= 1)
            dl += __shfl_down(dl, off);
        if ((tid & 63) == 0) atomicAdd(loss_acc, dl);
    }
}

__global__ void vq_fin(const double* __restrict__ loss_acc, float* __restrict__ out) {
    if (threadIdx.x == 0)
        out[N_ROWS * DIM] = (float)(1.25 * loss_acc[0] * (1.0 / (double)(N_ROWS * DIM)));
}

extern "C" void kernel_launch(void* const* d_in, const int* in_sizes, int n_in,
                              void* d_out, int out_size, void* d_ws, size_t ws_size,
                              hipStream_t stream) {
    const float* x   = (const float*)d_in[0];
    const float* emb = (const float*)d_in[1];
    float*  out  = (float*)d_out;
    float*  ws_f = (float*)d_ws;
    double* ws_d = (double*)d_ws;

    vq_prep<<<1, 512, 0, stream>>>(emb, ws_f, ws_d);
    vq_main<<<N_ROWS / ROWS_PER_BLOCK, THREADS, 0, stream>>>(x, ws_f, out, ws_d);
    vq_fin<<<1, 1, 0, stream>>>(ws_d, out);
}

// Round 5
// 65.670 us; speedup vs baseline: 1.4967x; 1.4967x over previous
//
#include <hip/hip_runtime.h>

// VectorQuantizer forward via bf16-split MFMA:
//   x          [64,32,32,64] f32  -> flat [N=65536, D=64]
//   embeddings [D=64, K=512] f32  (codes are COLUMNS)
//   out = x + (q - x),  q = argmin_k ||f - e_k||^2 ;  loss = 1.25*mean((q-x)^2)
//
// argmin_k ||f-e_k||^2 == argmin_k (en2[k] - 2 f.e_k)  (row term r2 is common).
// dot computed as fh*eh + fh*el + fl*eh with f=fh+fl, e=eh+el bf16 splits
// (|err| ~1e-5). Rows whose approx top-2 gap < TAU get an exact f32 rescan
// with arithmetic identical to the validated round-2 kernel.
//
// Fragment-ordered bf16 row data (Xhl) is staged in d_out: block b reads only
// rows [b*256, b*256+256) and overwrites the same region with output later.

#define N_ROWS 65536
#define DIM 64
#define KCODES 512

typedef short s16x8 __attribute__((ext_vector_type(8)));
typedef float f32x4 __attribute__((ext_vector_type(4)));

// ws byte offsets (total need ~261 KB)
#define LOSS_OFF   0
#define EN2_OFF    256
#define EN2B_OFF   2304
#define ET_OFF     4352
#define AFR_OFF    135424

#define TAU 1.2e-3f

__device__ __forceinline__ unsigned short f2bf(float f) {
    unsigned u = __float_as_uint(f);
    return (unsigned short)((u + 0x7fffu + ((u >> 16) & 1u)) >> 16);
}
__device__ __forceinline__ float bf2f(unsigned short h) {
    return __uint_as_float(((unsigned)h) << 16);
}

// ---------------- prep: codebook (blocks 0-1) + x->frag bf16 (blocks 2..1025)
__global__ void vq_prep(const float* __restrict__ x, const float* __restrict__ emb,
                        float* __restrict__ outbuf, char* __restrict__ ws) {
    const int bid = blockIdx.x, tid = threadIdx.x;
    if (bid < 2) {
        const int k = bid * 256 + tid;             // code 0..511
        if (k == 0) *(double*)(ws + LOSS_OFF) = 0.0;
        float* en2  = (float*)(ws + EN2_OFF);
        float* en2b = (float*)(ws + EN2B_OFF);
        float* eT   = (float*)(ws + ET_OFF);
        uint4* Afr  = (uint4*)(ws + AFR_OFF);
        const int ctg = k >> 4, c = k & 15;
        float s = 0.0f;
        #pragma unroll
        for (int ks = 0; ks < 2; ++ks) {
            #pragma unroll
            for (int g = 0; g < 4; ++g) {
                unsigned short hb[8], lb[8];
                #pragma unroll
                for (int j = 0; j < 8; ++j) {
                    const int d = ks * 32 + g * 8 + j;
                    const float v = emb[d * KCODES + k];   // coalesced across k
                    eT[k * DIM + d] = v;
                    s = fmaf(v, v, s);                     // same chain as round-2
                    const unsigned short h = f2bf(v);
                    hb[j] = h;
                    lb[j] = f2bf(v - bf2f(h));
                }
                uint4 H, L;
                H.x = hb[0] | ((unsigned)hb[1] << 16); H.y = hb[2] | ((unsigned)hb[3] << 16);
                H.z = hb[4] | ((unsigned)hb[5] << 16); H.w = hb[6] | ((unsigned)hb[7] << 16);
                L.x = lb[0] | ((unsigned)lb[1] << 16); L.y = lb[2] | ((unsigned)lb[3] << 16);
                L.z = lb[4] | ((unsigned)lb[5] << 16); L.w = lb[6] | ((unsigned)lb[7] << 16);
                const int lane = g * 16 + c;
                Afr[((ctg * 2 + ks) * 2 + 0) * 64 + lane] = H;
                Afr[((ctg * 2 + ks) * 2 + 1) * 64 + lane] = L;
            }
        }
        en2[k] = s;
        en2b[k] = s + 4.0f;   // bias so (en2b - 2dot) > 0 -> bit-monotone pack
    } else {
        const int rt   = (bid - 2) * 4 + (tid >> 6);   // row-tile 0..4095
        const int lane = tid & 63;
        const int row  = rt * 16 + (lane & 15);
        const int g    = lane >> 4;
        uint4* X = (uint4*)outbuf;
        #pragma unroll
        for (int ks = 0; ks < 2; ++ks) {
            const float* p = x + (size_t)row * DIM + ks * 32 + g * 8;
            const float4 v0 = *(const float4*)p;
            const float4 v1 = *(const float4*)(p + 4);
            float vv[8] = {v0.x, v0.y, v0.z, v0.w, v1.x, v1.y, v1.z, v1.w};
            unsigned short hb[8], lb[8];
            #pragma unroll
            for (int j = 0; j < 8; ++j) {
                const unsigned short h = f2bf(vv[j]);
                hb[j] = h;
                lb[j] = f2bf(vv[j] - bf2f(h));
            }
            uint4 H, L;
            H.x = hb[0] | ((unsigned)hb[1] << 16); H.y = hb[2] | ((unsigned)hb[3] << 16);
            H.z = hb[4] | ((unsigned)hb[5] << 16); H.w = hb[6] | ((unsigned)hb[7] << 16);
            L.x = lb[0] | ((unsigned)lb[1] << 16); L.y = lb[2] | ((unsigned)lb[3] << 16);
            L.z = lb[4] | ((unsigned)lb[5] << 16); L.w = lb[6] | ((unsigned)lb[7] << 16);
            X[((rt * 2 + ks) * 2 + 0) * 64 + lane] = H;
            X[((rt * 2 + ks) * 2 + 1) * 64 + lane] = L;
        }
    }
}

// ---------------- main: MFMA distances + argmin + exact fallback + out/loss
__global__ __launch_bounds__(512, 2)
void vq_main(const float* __restrict__ x, const char* __restrict__ ws,
             float* __restrict__ out, double* __restrict__ loss_acc) {
    __shared__ unsigned long long sm_all[16][8][16];
    __shared__ unsigned pick[256];
    __shared__ unsigned short llist[256];
    __shared__ int lcnt;

    const int tid = threadIdx.x;
    const int bid = blockIdx.x;
    const int w = __builtin_amdgcn_readfirstlane(tid >> 6);  // wave 0..7 = 64-code group
    const int l = tid & 63;
    if (tid == 0) lcnt = 0;

    // A-fragments: this wave's 64 codes (4 ctiles) x 2 ksteps x {hi,lo}
    const s16x8* Afr = (const s16x8*)(ws + AFR_OFF);
    s16x8 Aeh[4][2], Ael[4][2];
    #pragma unroll
    for (int ct = 0; ct < 4; ++ct) {
        #pragma unroll
        for (int ks = 0; ks < 2; ++ks) {
            const int ctg = w * 4 + ct;
            Aeh[ct][ks] = Afr[((ctg * 2 + ks) * 2 + 0) * 64 + l];
            Ael[ct][ks] = Afr[((ctg * 2 + ks) * 2 + 1) * 64 + l];
        }
    }
    const float* en2b = (const float*)(ws + EN2B_OFF);
    f32x4 enf[4];
    #pragma unroll
    for (int ct = 0; ct < 4; ++ct) {
        const float4 t = *(const float4*)(en2b + w * 64 + ct * 16 + (l >> 4) * 4);
        enf[ct][0] = t.x; enf[ct][1] = t.y; enf[ct][2] = t.z; enf[ct][3] = t.w;
    }
    const int codebase = w * 64 + (l >> 4) * 4;

    __syncthreads();

    const s16x8* Xf = (const s16x8*)out;   // frag-ordered rows, staged by prep

    #pragma unroll 2
    for (int bt = 0; bt < 16; ++bt) {
        const int rt = bid * 16 + bt;
        const s16x8 bh0 = Xf[((rt * 2 + 0) * 2 + 0) * 64 + l];
        const s16x8 bh1 = Xf[((rt * 2 + 1) * 2 + 0) * 64 + l];
        const s16x8 bl0 = Xf[((rt * 2 + 0) * 2 + 1) * 64 + l];
        const s16x8 bl1 = Xf[((rt * 2 + 1) * 2 + 1) * 64 + l];
        f32x4 acc[4];
        #pragma unroll
        for (int ct = 0; ct < 4; ++ct) {
            f32x4 a = {0.f, 0.f, 0.f, 0.f};
            a = __builtin_amdgcn_mfma_f32_16x16x32_bf16(Aeh[ct][0], bh0, a, 0, 0, 0);
            a = __builtin_amdgcn_mfma_f32_16x16x32_bf16(Aeh[ct][1], bh1, a, 0, 0, 0);
            a = __builtin_amdgcn_mfma_f32_16x16x32_bf16(Ael[ct][0], bh0, a, 0, 0, 0);
            a = __builtin_amdgcn_mfma_f32_16x16x32_bf16(Ael[ct][1], bh1, a, 0, 0, 0);
            a = __builtin_amdgcn_mfma_f32_16x16x32_bf16(Aeh[ct][0], bl0, a, 0, 0, 0);
            a = __builtin_amdgcn_mfma_f32_16x16x32_bf16(Aeh[ct][1], bl1, a, 0, 0, 0);
            acc[ct] = a;
        }
        // min1/min2 over this lane's 16 (code, value) pairs, packed:
        // high 23 bits = f32 bits of (en2+4-2dot) masked, low 9 bits = code.
        unsigned m1 = 0xFFFFFFFFu, m2 = 0xFFFFFFFFu;
        #pragma unroll
        for (int ct = 0; ct < 4; ++ct) {
            #pragma unroll
            for (int rg = 0; rg < 4; ++rg) {
                const float m = fmaf(-2.0f, acc[ct][rg], enf[ct][rg]);
                const unsigned u = (__float_as_uint(m) & 0xFFFFFE00u)
                                 | (unsigned)(codebase + ct * 16 + rg);
                const unsigned hi = m1 > u ? m1 : u;
                m1 = m1 < u ? m1 : u;
                m2 = m2 < hi ? m2 : hi;
            }
        }
        #pragma unroll
        for (int mask = 16; mask <= 32; mask <<= 1) {
            const unsigned o1 = __shfl_xor(m1, mask);
            const unsigned o2 = __shfl_xor(m2, mask);
            const unsigned hi  = m1 > o1 ? m1 : o1;
            const unsigned lo2 = m2 < o2 ? m2 : o2;
            m1 = m1 < o1 ? m1 : o1;
            m2 = hi < lo2 ? hi : lo2;
        }
        if (l < 16) sm_all[bt][w][l] = ((unsigned long long)m1 << 32) | m2;
    }
    __syncthreads();

    // combine the 8 waves' results per row; flag near-ties for exact rescan
    if (tid < 256) {
        const int bt = tid >> 4, c = tid & 15;
        unsigned long long p = sm_all[bt][0][c];
        unsigned m1 = (unsigned)(p >> 32), m2 = (unsigned)p;
        #pragma unroll
        for (int w2 = 1; w2 < 8; ++w2) {
            p = sm_all[bt][w2][c];
            const unsigned a1 = (unsigned)(p >> 32), a2 = (unsigned)p;
            const unsigned hi  = m1 > a1 ? m1 : a1;
            const unsigned lo2 = m2 < a2 ? m2 : a2;
            m1 = m1 < a1 ? m1 : a1;
            m2 = hi < lo2 ? hi : lo2;
        }
        pick[tid] = m1 & 0x1FFu;
        const float f1 = __uint_as_float(m1 & 0xFFFFFE00u);
        const float f2 = __uint_as_float(m2 & 0xFFFFFE00u);
        if (f2 - f1 < TAU) {
            const int idx = atomicAdd(&lcnt, 1);
            llist[idx] = (unsigned short)tid;
        }
    }
    __syncthreads();

    // exact f32 fallback (round-2-identical arithmetic), one wave per row
    {
        const float* eT  = (const float*)(ws + ET_OFF);
        const float* en2 = (const float*)(ws + EN2_OFF);
        const int nfb = lcnt;
        for (int i = w; i < nfb; i += 8) {
            const int r = llist[i];
            const int grow = bid * 256 + r;
            const float4* xr = (const float4*)(x + (size_t)grow * DIM);
            float4 f[16];
            #pragma unroll
            for (int j = 0; j < 16; ++j) f[j] = xr[j];
            float4 a4 = make_float4(0.f, 0.f, 0.f, 0.f);
            #pragma unroll
            for (int j = 0; j < 16; ++j) {
                a4.x = fmaf(f[j].x, f[j].x, a4.x);
                a4.y = fmaf(f[j].y, f[j].y, a4.y);
                a4.z = fmaf(f[j].z, f[j].z, a4.z);
                a4.w = fmaf(f[j].w, f[j].w, a4.w);
            }
            const float r2 = (a4.x + a4.y) + (a4.z + a4.w);
            unsigned long long best = 0xFFFFFFFFFFFFFFFFull;
            #pragma unroll 2
            for (int c8 = 0; c8 < 8; ++c8) {
                const int k = l * 8 + c8;
                const float4* ek = (const float4*)(eT + k * DIM);
                float4 acc4 = make_float4(0.f, 0.f, 0.f, 0.f);
                #pragma unroll
                for (int j = 0; j < 16; ++j) {
                    const float4 e = ek[j];
                    acc4.x = fmaf(f[j].x, e.x, acc4.x);
                    acc4.y = fmaf(f[j].y, e.y, acc4.y);
                    acc4.z = fmaf(f[j].z, e.z, acc4.z);
                    acc4.w = fmaf(f[j].w, e.w, acc4.w);
                }
                const float dot = (acc4.x + acc4.y) + (acc4.z + acc4.w);
                const float s = (r2 + en2[k]) - 2.0f * dot;
                const unsigned long long pk =
                    ((unsigned long long)__float_as_uint(s) << 32) | (unsigned)k;
                if (pk < best) best = pk;   // ascending k + strict < == np.argmin
            }
            #pragma unroll
            for (int mask = 1; mask <= 32; mask <<= 1) {
                const unsigned long long o = __shfl_xor(best, mask);
                if (o < best) best = o;
            }
            if (l == 0) pick[r] = (unsigned)best & 0x1FFu;
        }
    }
    __syncthreads();

    // out = x + (q - x) and loss, overwriting this block's Xhl region
    {
        const float* eT = (const float*)(ws + ET_OFF);
        const int r = tid >> 1, hf = tid & 1;
        const int grow = bid * 256 + r;
        const float4* xr = (const float4*)(x + (size_t)grow * DIM) + hf * 8;
        const float4* qr = (const float4*)(eT + pick[r] * DIM) + hf * 8;
        float4* orow = ((float4*)out) + (size_t)grow * 16 + hf * 8;
        float lsum = 0.0f;
        #pragma unroll
        for (int j = 0; j < 8; ++j) {
            const float4 q = qr[j], xv = xr[j];
            float4 o; float dx;
            dx = q.x - xv.x; o.x = xv.x + dx; lsum = fmaf(dx, dx, lsum);
            dx = q.y - xv.y; o.y = xv.y + dx; lsum = fmaf(dx, dx, lsum);
            dx = q.z - xv.z; o.z = xv.z + dx; lsum = fmaf(dx, dx, lsum);
            dx = q.w - xv.w; o.w = xv.w + dx; lsum = fmaf(dx, dx, lsum);
            orow[j] = o;
        }
        double dl = (double)lsum;
        #pragma unroll
        for (int off = 32; off > 0; off >>= 1) dl += __shfl_down(dl, off);
        if (l == 0) atomicAdd(loss_acc, dl);
    }
}

__global__ void vq_fin(const double* __restrict__ loss_acc, float* __restrict__ out) {
    if (threadIdx.x == 0)
        out[N_ROWS * DIM] = (float)(1.25 * loss_acc[0] * (1.0 / (double)(N_ROWS * DIM)));
}

extern "C" void kernel_launch(void* const* d_in, const int* in_sizes, int n_in,
                              void* d_out, int out_size, void* d_ws, size_t ws_size,
                              hipStream_t stream) {
    const float* x   = (const float*)d_in[0];
    const float* emb = (const float*)d_in[1];
    float* out = (float*)d_out;
    char*  ws  = (char*)d_ws;

    vq_prep<<<1026, 256, 0, stream>>>(x, emb, out, ws);
    vq_main<<<256, 512, 0, stream>>>(x, ws, out, (double*)(ws + LOSS_OFF));
    vq_fin<<<1, 1, 0, stream>>>((const double*)(ws + LOSS_OFF), out);
}